// Round 4
// baseline (263.696 us; speedup 1.0000x reference)
//
#include <hip/hip_runtime.h>

#define S_LEN 2048
#define NH 16
#define DIM 128
#define KSZ 32
#define STRD 16
#define SSZ 64
#define NSELB 32
#define NCMP 127
#define TOPN 16
#define WINSZ 512
#define NEGF (-1e30f)
#define NEGTH (-1e29f)
#define SCALE 0.088388347648318447f

typedef __attribute__((ext_vector_type(8))) short bf16x8;
typedef __attribute__((ext_vector_type(4))) float f32x4;

__device__ __forceinline__ unsigned short f2bf(float f) {
  unsigned u = __builtin_bit_cast(unsigned, f);
  return (unsigned short)((u + 0x7FFFu + ((u >> 16) & 1u)) >> 16);
}
__device__ __forceinline__ float bf2f(unsigned short b) {
  return __builtin_bit_cast(float, (unsigned)b << 16);
}
__device__ __forceinline__ bf16x8 pack8(const float* f) {
  bf16x8 r;
#pragma unroll
  for (int i = 0; i < 8; ++i) r[i] = (short)f2bf(f[i]);
  return r;
}

// ---------- kernel 1: build vtg[h][d][t] (V^T) and kb[t][h][d], both bf16 ----------
__global__ __launch_bounds__(256) void nsa_build(
    const float* __restrict__ v, const float* __restrict__ k,
    unsigned short* __restrict__ vtg, unsigned short* __restrict__ kb) {
  const int c = blockIdx.x * 256 + threadIdx.x;   // 524288 chunks of 8
  {
    const int h = c >> 15, rem = c & 32767;
    const int d = rem >> 8, tc = rem & 255;
    float f[8];
#pragma unroll
    for (int i = 0; i < 8; ++i) f[i] = v[((tc * 8 + i) * NH + h) * DIM + d];
    *(bf16x8*)(vtg + ((h * DIM + d) * S_LEN + tc * 8)) = pack8(f);
  }
  {
    const int t = c >> 8, h2 = (c >> 4) & 15, dc = c & 15;
    const float* src = k + ((t * NH + h2) * DIM + dc * 8);
    float f[8];
#pragma unroll
    for (int i = 0; i < 8; ++i) f[i] = src[i];
    *(bf16x8*)(kb + (t * NH + h2) * DIM + dc * 8) = pack8(f);
  }
}

// ---------- kernel 2: compress; cmpk as hi/lo bf16 pair, cmpv transposed bf16 ----------
__global__ __launch_bounds__(128) void nsa_compress(
    const float* __restrict__ k, const float* __restrict__ v,
    unsigned short* __restrict__ cmpkh, unsigned short* __restrict__ cmpkl,
    unsigned short* __restrict__ cmpvt) {
  const int c = blockIdx.x & 127;
  const int h = blockIdx.x >> 7;
  const int d = threadIdx.x;
  float sk = 0.f, sv = 0.f;
  if (c < NCMP) {
    const int base = ((c * STRD) * NH + h) * DIM + d;
#pragma unroll
    for (int i = 0; i < KSZ; ++i) {
      sk += k[base + i * NH * DIM];
      sv += v[base + i * NH * DIM];
    }
    sk *= (1.0f / KSZ); sv *= (1.0f / KSZ);
  }
  const unsigned short hi = f2bf(sk);
  const unsigned short lo = f2bf(sk - bf2f(hi));
  cmpkh[(h * 128 + c) * 128 + d] = (c < NCMP) ? hi : 0;
  cmpkl[(h * 128 + c) * 128 + d] = (c < NCMP) ? lo : 0;
  cmpvt[(h * 128 + d) * 128 + c] = (c < NCMP) ? f2bf(sv) : 0;
}

// ---------- kernel 3: main fused NSA ----------
__global__ __launch_bounds__(256, 2) void nsa_main(
    const float* __restrict__ q, const float* __restrict__ wg,
    const float* __restrict__ bg, const unsigned short* __restrict__ kb,
    const unsigned short* __restrict__ vtg,
    const unsigned short* __restrict__ cmpkh, const unsigned short* __restrict__ cmpkl,
    const unsigned short* __restrict__ cmpvt, float* __restrict__ out) {
  __shared__ __align__(16) char klds[32 * 256];      // [32 keys][128 d] bf16, XOR swizzle
  __shared__ __align__(16) char vt[128 * 80];        // [128 d][32 keys] bf16 (stride 80B); aliases K-lo in pass A
  __shared__ __align__(16) float sc[4 * 16 * 132];   // per-wave [16 q][128+pad] f32
  __shared__ __align__(16) char pa[4 * 2048];        // per-wave P bf16 / ssel alias
  __shared__ unsigned maskLds[64];
  __shared__ unsigned unionLds;
  __shared__ float gatesLds[192];

  const int h = blockIdx.x >> 5;
  const int t0 = (blockIdx.x & 31) * 64;
  const int tid = threadIdx.x;
  const int lane = tid & 63;
  const int w = tid >> 6;
  const int l15 = lane & 15;
  const int l4 = lane >> 4;

  float* scw = sc + w * 16 * 132;
  char* paw = pa + w * 2048;
  char* kldsL = vt;                                  // pass-A-only alias

  if (tid < 64) maskLds[tid] = 0u;
  if (tid == 64) unionLds = 0u;

  // ---- gates (fp32, exact) ----
  {
    const int qloc = tid >> 2, g = tid & 3;
    if (g < 3) {
      const float* qr = q + ((t0 + qloc) * NH + h) * DIM;
      float acc = bg[g];
#pragma unroll
      for (int d4 = 0; d4 < DIM; d4 += 4) {
        const float4 qv = *(const float4*)(qr + d4);
        acc += qv.x * wg[(d4 + 0) * 3 + g] + qv.y * wg[(d4 + 1) * 3 + g] +
               qv.z * wg[(d4 + 2) * 3 + g] + qv.w * wg[(d4 + 3) * 3 + g];
      }
      gatesLds[qloc * 3 + g] = 1.0f / (1.0f + __expf(-acc));
    }
  }

  // ---- Q fragments: hi (kept) and lo (pass A only) ----
  bf16x8 qfh[4], qfl[4];
  {
    const float* qp = q + ((t0 + w * 16 + l15) * NH + h) * DIM + l4 * 8;
#pragma unroll
    for (int ks = 0; ks < 4; ++ks) {
      float fh[8], fl[8];
#pragma unroll
      for (int i = 0; i < 8; ++i) {
        const float x = qp[ks * 32 + i];
        const unsigned short hb = f2bf(x);
        fh[i] = bf2f(hb);
        fl[i] = x - fh[i];
      }
      qfh[ks] = pack8(fh);
      qfl[ks] = pack8(fl);
    }
  }

  // ================= compressed branch: Pass A (hi/lo QK -> sc) =================
  for (int ct = 0; ct < 4; ++ct) {
    __syncthreads();
#pragma unroll
    for (int c = 0; c < 2; ++c) {
      const int e = tid + c * 256;
      const int key = e >> 4, dc = e & 15;
      const int swz = key * 256 + ((dc * 16) ^ ((key & 7) << 4));
      const int src = (h * 128 + ct * 32 + key) * 128 + dc * 8;
      *(bf16x8*)(klds + swz) = *(const bf16x8*)(cmpkh + src);
      *(bf16x8*)(kldsL + swz) = *(const bf16x8*)(cmpkl + src);
    }
    __syncthreads();
    f32x4 s0 = {0, 0, 0, 0}, s1 = {0, 0, 0, 0};
#pragma unroll
    for (int ks = 0; ks < 4; ++ks) {
      const int db = ks * 64 + l4 * 16;
      const int o0 = l15 * 256 + (db ^ ((l15 & 7) << 4));
      const int o1 = (16 + l15) * 256 + (db ^ (((16 + l15) & 7) << 4));
      bf16x8 bh0 = *(const bf16x8*)(klds + o0);
      bf16x8 bh1 = *(const bf16x8*)(klds + o1);
      bf16x8 bl0 = *(const bf16x8*)(kldsL + o0);
      bf16x8 bl1 = *(const bf16x8*)(kldsL + o1);
      s0 = __builtin_amdgcn_mfma_f32_16x16x32_bf16(qfh[ks], bh0, s0, 0, 0, 0);
      s0 = __builtin_amdgcn_mfma_f32_16x16x32_bf16(qfl[ks], bh0, s0, 0, 0, 0);
      s0 = __builtin_amdgcn_mfma_f32_16x16x32_bf16(qfh[ks], bl0, s0, 0, 0, 0);
      s1 = __builtin_amdgcn_mfma_f32_16x16x32_bf16(qfh[ks], bh1, s1, 0, 0, 0);
      s1 = __builtin_amdgcn_mfma_f32_16x16x32_bf16(qfl[ks], bh1, s1, 0, 0, 0);
      s1 = __builtin_amdgcn_mfma_f32_16x16x32_bf16(qfh[ks], bl1, s1, 0, 0, 0);
    }
#pragma unroll
    for (int j = 0; j < 4; ++j) {
      const int qr = l4 * 4 + j;
      scw[qr * 132 + ct * 32 + l15] = s0[j] * SCALE;
      scw[qr * 132 + ct * 32 + 16 + l15] = s1[j] * SCALE;
    }
  }
  __syncthreads();

  // ---- exact softmax over 127 cmp scores (4 lanes per query) ----
  {
    const int qq = lane >> 2, qg = lane & 3;
    const int tq = t0 + w * 16 + qq;
    const int nv = (tq >= KSZ - 1) ? ((tq - (KSZ - 1)) / STRD + 1) : 0;
    float x[32];
#pragma unroll
    for (int i = 0; i < 32; ++i) x[i] = scw[qq * 132 + qg * 32 + i];
    float m = NEGF;
#pragma unroll
    for (int i = 0; i < 32; ++i) {
      const int c = qg * 32 + i;
      if (c < nv) m = fmaxf(m, x[i]);
    }
    m = fmaxf(m, __shfl_xor(m, 1));
    m = fmaxf(m, __shfl_xor(m, 2));
    float s = 0.f;
#pragma unroll
    for (int i = 0; i < 32; ++i) {
      const int c = qg * 32 + i;
      x[i] = (c < nv) ? __expf(x[i] - m) : 0.f;
      s += x[i];
    }
    s += __shfl_xor(s, 1);
    s += __shfl_xor(s, 2);
    const float inv = (nv > 0) ? (1.0f / s) : 0.f;
#pragma unroll
    for (int i = 0; i < 32; ++i) scw[qq * 132 + qg * 32 + i] = x[i] * inv;
  }
  __syncthreads();

  // ---- selection scores + top-16 (exact tie semantics) ----
  {
    const int qq = lane >> 2, jg = lane & 3;
    const int tq = t0 + w * 16 + qq;
    float* ss = (float*)paw;
    float vj[8];
#pragma unroll
    for (int i = 0; i < 8; ++i) {
      const int j = jg * 8 + i;
      const int lo = (4 * j - 1 > 0) ? 4 * j - 1 : 0;
      const int hi = (4 * j + 3 < NCMP - 1) ? 4 * j + 3 : NCMP - 1;
      float ps = 0.f;
      for (int c = lo; c <= hi; ++c) ps += scw[qq * 132 + c];
      float val = (j * SSZ <= tq) ? ps : -1.0f;
      if (j == (tq >> 6)) val += 1e6f;
      vj[i] = val;
      ss[qq * 32 + j] = val;
    }
    __syncthreads();
#pragma unroll
    for (int i = 0; i < 8; ++i) {
      const int j = jg * 8 + i;
      const float my = vj[i];
      int rank = 0;
      for (int jp = 0; jp < NSELB; ++jp) {
        const float o = ss[qq * 32 + jp];
        rank += (o > my) || (o == my && jp < j);
      }
      if (rank < TOPN && (j * SSZ <= tq)) {
        atomicOr(&maskLds[w * 16 + qq], 1u << j);
        atomicOr(&unionLds, 1u << j);
      }
    }
  }
  __syncthreads();

  unsigned maskq[4];
#pragma unroll
  for (int j = 0; j < 4; ++j) maskq[j] = maskLds[w * 16 + l4 * 4 + j];
  const unsigned unionMask = unionLds;

  // ================= compressed branch: Pass B (PV) =================
  f32x4 accA[8], accB[8], ocmp[8];
#pragma unroll
  for (int n = 0; n < 8; ++n) accA[n] = (f32x4){0, 0, 0, 0};
  for (int ct = 0; ct < 4; ++ct) {
    __syncthreads();
#pragma unroll
    for (int c = 0; c < 2; ++c) {
      const int e = tid + c * 256;
      const int d = e >> 2, kc = e & 3;
      *(bf16x8*)(vt + d * 80 + kc * 16) =
          *(const bf16x8*)(cmpvt + (h * 128 + d) * 128 + ct * 32 + kc * 8);
    }
    __syncthreads();
    float f[8];
#pragma unroll
    for (int i = 0; i < 8; ++i) f[i] = scw[l15 * 132 + ct * 32 + l4 * 8 + i];
    bf16x8 ap = pack8(f);
#pragma unroll
    for (int n = 0; n < 8; ++n) {
      bf16x8 bv = *(const bf16x8*)(vt + (n * 16 + l15) * 80 + l4 * 16);
      accA[n] = __builtin_amdgcn_mfma_f32_16x16x32_bf16(ap, bv, accA[n], 0, 0, 0);
    }
  }
  // Ocmp -> registers (scw free afterwards)
#pragma unroll
  for (int j = 0; j < 4; ++j) {
    const float g0 = gatesLds[(w * 16 + l4 * 4 + j) * 3 + 0];
#pragma unroll
    for (int n = 0; n < 8; ++n) ocmp[n][j] = g0 * accA[n][j];
  }

  // ================= main pass: selected + window =================
  float mS[4], lS[4], mW[4], lW[4];
#pragma unroll
  for (int j = 0; j < 4; ++j) { mS[j] = NEGF; lS[j] = 0.f; mW[j] = NEGF; lW[j] = 0.f; }
#pragma unroll
  for (int n = 0; n < 8; ++n) { accA[n] = (f32x4){0, 0, 0, 0}; accB[n] = (f32x4){0, 0, 0, 0}; }

  const int ktmax = (t0 + 63) >> 5;
  for (int kt = 0; kt <= ktmax; ++kt) {
    const int kt0 = kt * 32;
    const int jb = kt >> 1;
    const bool selAny = (unionMask >> jb) & 1u;
    const bool winAny = (kt0 + 31) >= (t0 - WINSZ);
    if (!selAny && !winAny) continue;
    __syncthreads();
    // stage K tile (bf16 direct, swizzled)
#pragma unroll
    for (int c = 0; c < 2; ++c) {
      const int e = tid + c * 256;
      const int key = e >> 4, dc = e & 15;
      *(bf16x8*)(klds + key * 256 + ((dc * 16) ^ ((key & 7) << 4))) =
          *(const bf16x8*)(kb + ((kt0 + key) * NH + h) * DIM + dc * 8);
    }
    // stage V tile from vtg
#pragma unroll
    for (int c = 0; c < 2; ++c) {
      const int e = tid + c * 256;
      const int d = e >> 2, kc = e & 3;
      *(bf16x8*)(vt + d * 80 + kc * 16) =
          *(const bf16x8*)(vtg + (h * DIM + d) * S_LEN + kt0 + kc * 8);
    }
    __syncthreads();

    // shared QK
    f32x4 s0 = {0, 0, 0, 0}, s1 = {0, 0, 0, 0};
#pragma unroll
    for (int ks = 0; ks < 4; ++ks) {
      const int db = ks * 64 + l4 * 16;
      bf16x8 b0 = *(const bf16x8*)(klds + l15 * 256 + (db ^ ((l15 & 7) << 4)));
      bf16x8 b1 = *(const bf16x8*)(klds + (16 + l15) * 256 + (db ^ (((16 + l15) & 7) << 4)));
      s0 = __builtin_amdgcn_mfma_f32_16x16x32_bf16(qfh[ks], b0, s0, 0, 0, 0);
      s1 = __builtin_amdgcn_mfma_f32_16x16x32_bf16(qfh[ks], b1, s1, 0, 0, 0);
    }
#pragma unroll
    for (int j = 0; j < 4; ++j) { s0[j] *= SCALE; s1[j] *= SCALE; }
    const int c0 = kt0 + l15, c1 = kt0 + 16 + l15;

    // ---- selected branch ----
    if (selAny) {
#pragma unroll
      for (int j = 0; j < 4; ++j) {
        const int qr = l4 * 4 + j;
        const int tq = t0 + w * 16 + qr;
        const bool mb = (maskq[j] >> jb) & 1u;
        const float v0 = (mb && c0 <= tq) ? s0[j] : NEGF;
        const float v1 = (mb && c1 <= tq) ? s1[j] : NEGF;
        float rm = fmaxf(v0, v1);
        rm = fmaxf(rm, __shfl_xor(rm, 1));
        rm = fmaxf(rm, __shfl_xor(rm, 2));
        rm = fmaxf(rm, __shfl_xor(rm, 4));
        rm = fmaxf(rm, __shfl_xor(rm, 8));
        if (rm > mS[j]) {                       // exact defer-rescale
          const float sf = __expf(mS[j] - rm);
          lS[j] *= sf;
#pragma unroll
          for (int n = 0; n < 8; ++n) accA[n][j] *= sf;
          mS[j] = rm;
        }
        const float p0 = (v0 > NEGTH) ? __expf(v0 - mS[j]) : 0.f;
        const float p1 = (v1 > NEGTH) ? __expf(v1 - mS[j]) : 0.f;
        float rs = p0 + p1;
        rs += __shfl_xor(rs, 1);
        rs += __shfl_xor(rs, 2);
        rs += __shfl_xor(rs, 4);
        rs += __shfl_xor(rs, 8);
        lS[j] += rs;
        *(unsigned short*)(paw + qr * 128 + ((l15 * 2) ^ ((qr & 7) << 4))) = f2bf(p0);
        *(unsigned short*)(paw + qr * 128 + (((16 + l15) * 2) ^ ((qr & 7) << 4))) = f2bf(p1);
      }
      bf16x8 ap = *(const bf16x8*)(paw + l15 * 128 + ((l4 * 16) ^ ((l15 & 7) << 4)));
#pragma unroll
      for (int n = 0; n < 8; ++n) {
        bf16x8 bv = *(const bf16x8*)(vt + (n * 16 + l15) * 80 + l4 * 16);
        accA[n] = __builtin_amdgcn_mfma_f32_16x16x32_bf16(ap, bv, accA[n], 0, 0, 0);
      }
    }
    // ---- window branch ----
    if (winAny) {
#pragma unroll
      for (int j = 0; j < 4; ++j) {
        const int qr = l4 * 4 + j;
        const int tq = t0 + w * 16 + qr;
        const float v0 = (c0 <= tq && c0 >= tq - WINSZ) ? s0[j] : NEGF;
        const float v1 = (c1 <= tq && c1 >= tq - WINSZ) ? s1[j] : NEGF;
        float rm = fmaxf(v0, v1);
        rm = fmaxf(rm, __shfl_xor(rm, 1));
        rm = fmaxf(rm, __shfl_xor(rm, 2));
        rm = fmaxf(rm, __shfl_xor(rm, 4));
        rm = fmaxf(rm, __shfl_xor(rm, 8));
        if (rm > mW[j]) {
          const float sf = __expf(mW[j] - rm);
          lW[j] *= sf;
#pragma unroll
          for (int n = 0; n < 8; ++n) accB[n][j] *= sf;
          mW[j] = rm;
        }
        const float p0 = (v0 > NEGTH) ? __expf(v0 - mW[j]) : 0.f;
        const float p1 = (v1 > NEGTH) ? __expf(v1 - mW[j]) : 0.f;
        float rs = p0 + p1;
        rs += __shfl_xor(rs, 1);
        rs += __shfl_xor(rs, 2);
        rs += __shfl_xor(rs, 4);
        rs += __shfl_xor(rs, 8);
        lW[j] += rs;
        *(unsigned short*)(paw + qr * 128 + ((l15 * 2) ^ ((qr & 7) << 4))) = f2bf(p0);
        *(unsigned short*)(paw + qr * 128 + (((16 + l15) * 2) ^ ((qr & 7) << 4))) = f2bf(p1);
      }
      bf16x8 ap = *(const bf16x8*)(paw + l15 * 128 + ((l4 * 16) ^ ((l15 & 7) << 4)));
#pragma unroll
      for (int n = 0; n < 8; ++n) {
        bf16x8 bv = *(const bf16x8*)(vt + (n * 16 + l15) * 80 + l4 * 16);
        accB[n] = __builtin_amdgcn_mfma_f32_16x16x32_bf16(ap, bv, accB[n], 0, 0, 0);
      }
    }
  }

  // ---- epilogue: combine ----
#pragma unroll
  for (int j = 0; j < 4; ++j) {
    const int qr = l4 * 4 + j;
    const int tq = t0 + w * 16 + qr;
    const float g1 = gatesLds[(w * 16 + qr) * 3 + 1];
    const float g2 = gatesLds[(w * 16 + qr) * 3 + 2];
    const float rlS = 1.0f / lS[j];
    const float rlW = 1.0f / lW[j];
#pragma unroll
    for (int n = 0; n < 8; ++n) {
      out[(tq * NH + h) * DIM + n * 16 + l15] =
          ocmp[n][j] + g1 * accA[n][j] * rlS + g2 * accB[n][j] * rlW;
    }
  }
}

extern "C" void kernel_launch(void* const* d_in, const int* in_sizes, int n_in,
                              void* d_out, int out_size, void* d_ws, size_t ws_size,
                              hipStream_t stream) {
  const float* q  = (const float*)d_in[0];
  const float* k  = (const float*)d_in[1];
  const float* v  = (const float*)d_in[2];
  const float* wg = (const float*)d_in[3];
  const float* bg = (const float*)d_in[4];
  float* out = (float*)d_out;

  unsigned short* vtg   = (unsigned short*)d_ws;            // 8 MB
  unsigned short* kb    = vtg + NH * DIM * S_LEN;           // 8 MB
  unsigned short* cmpkh = kb + S_LEN * NH * DIM;            // 512 KB
  unsigned short* cmpkl = cmpkh + NH * 128 * 128;           // 512 KB
  unsigned short* cmpvt = cmpkl + NH * 128 * 128;           // 512 KB

  nsa_build<<<2048, 256, 0, stream>>>(v, k, vtg, kb);
  nsa_compress<<<NH * 128, 128, 0, stream>>>(k, v, cmpkh, cmpkl, cmpvt);
  nsa_main<<<NH * 32, 256, 0, stream>>>(q, wg, bg, kb, vtg, cmpkh, cmpkl, cmpvt, out);
}